// Round 3
// baseline (88.101 us; speedup 1.0000x reference)
//
#include <hip/hip_runtime.h>

#define HW_   (512*512)         // 262144 pixels per image
#define NC    16
#define GPB4  (HW_/4)           // 65536 float4-groups per image (2^16)
#define NBLK  2048              // 2048*256 threads = 524288 = total groups (8*HW_/4)
#define NTHR  256
#define NBUK  16                // bucket rows for global partials

// ws layout (floats): [NBUK][48] partials; ws[NBUK*48] = block counter (int)
// stat s: 0..15 = p_sum[c], 16..31 = intersection[c], 32..47 = t_sum[c]

__device__ __forceinline__ float wred(float v) {
    v += __shfl_xor(v, 32, 64);
    v += __shfl_xor(v, 16, 64);
    v += __shfl_xor(v,  8, 64);
    v += __shfl_xor(v,  4, 64);
    v += __shfl_xor(v,  2, 64);
    v += __shfl_xor(v,  1, 64);
    return v;
}

__global__ __launch_bounds__(NTHR, 4) void dice_main(
        const float* __restrict__ logits,
        const int*   __restrict__ targets,
        float*       __restrict__ ws,
        float*       __restrict__ out) {
    __shared__ float red[4][48];
    __shared__ float fin[48];
    __shared__ int   isLast;

    const int tid = threadIdx.x;
    const int g   = blockIdx.x * NTHR + tid;       // one float4-group per thread
    const int b   = g >> 16;                       // g / GPB4
    const int s4  = g & (GPB4 - 1);                // g % GPB4

    const float4* lp = reinterpret_cast<const float4*>(logits) + (size_t)b * (NC * GPB4) + s4;
    const int4 t = reinterpret_cast<const int4*>(targets)[(size_t)b * GPB4 + s4];

    // ---- 16 independent coalesced float4 loads, then exps ----
    float4 e[NC];
    float sx = 0.f, sy = 0.f, sz = 0.f, sw = 0.f;
    #pragma unroll
    for (int c = 0; c < NC; ++c) {
        const float4 l = lp[(size_t)c * GPB4];
        e[c].x = __expf(l.x); e[c].y = __expf(l.y);
        e[c].z = __expf(l.z); e[c].w = __expf(l.w);
        sx += e[c].x; sy += e[c].y; sz += e[c].z; sw += e[c].w;
    }
    const float ix = __builtin_amdgcn_rcpf(sx);
    const float iy = __builtin_amdgcn_rcpf(sy);
    const float iz = __builtin_amdgcn_rcpf(sz);
    const float iw = __builtin_amdgcn_rcpf(sw);

    // ---- per-class stats + immediate wave reduction (frees e[c] as we go) ----
    const int lane = tid & 63, wv = tid >> 6;
    #pragma unroll
    for (int c = 0; c < NC; ++c) {
        const float px = e[c].x * ix, py = e[c].y * iy;
        const float pz = e[c].z * iz, pw = e[c].w * iw;
        const float ps = (px + py) + (pz + pw);
        const float ic = (t.x == c ? px : 0.f) + (t.y == c ? py : 0.f)
                       + (t.z == c ? pz : 0.f) + (t.w == c ? pw : 0.f);
        const float tc = (t.x == c ? 1.f : 0.f) + (t.y == c ? 1.f : 0.f)
                       + (t.z == c ? 1.f : 0.f) + (t.w == c ? 1.f : 0.f);
        const float rp = wred(ps);
        const float ri = wred(ic);
        const float rt = wred(tc);
        if (lane == 0) { red[wv][c] = rp; red[wv][16 + c] = ri; red[wv][32 + c] = rt; }
    }
    __syncthreads();

    if (tid < 48) {
        const float v = red[0][tid] + red[1][tid] + red[2][tid] + red[3][tid];
        atomicAdd(&ws[(blockIdx.x & (NBUK - 1)) * 48 + tid], v);
        __threadfence();
    }
    __syncthreads();

    // ---- last-block finalize ----
    if (tid == 0) {
        const int old = atomicAdd((int*)(ws + NBUK * 48), 1);
        isLast = (old == NBLK - 1);
    }
    __syncthreads();
    if (!isLast) return;

    __threadfence();
    if (tid < 48) {
        float s = 0.f;
        #pragma unroll
        for (int k = 0; k < NBUK; ++k)
            s += atomicAdd(&ws[k * 48 + tid], 0.0f);   // device-scope coherent read
        fin[tid] = s;
    }
    __syncthreads();
    if (tid == 0) {
        float acc = 0.f;
        #pragma unroll
        for (int c = 0; c < NC; ++c) {
            const float dice = (2.f * fin[16 + c] + 1.f) / (fin[c] + fin[32 + c] + 1.f);
            acc += 1.f - dice;
        }
        out[0] = acc * (1.f / 16.f);
    }
}

extern "C" void kernel_launch(void* const* d_in, const int* in_sizes, int n_in,
                              void* d_out, int out_size, void* d_ws, size_t ws_size,
                              hipStream_t stream) {
    const float* logits  = (const float*)d_in[0];
    const int*   targets = (const int*)d_in[1];
    float* ws  = (float*)d_ws;
    float* out = (float*)d_out;

    hipMemsetAsync(ws, 0, 4096, stream);   // buckets + counter
    dice_main<<<NBLK, NTHR, 0, stream>>>(logits, targets, ws, out);
}

// Round 4
// 64.174 us; speedup vs baseline: 1.3728x; 1.3728x over previous
//
#include <hip/hip_runtime.h>

#define HW_    (512*512)       // 262144 pixels per image
#define NC     16
#define GPB4   (HW_/4)         // 65536 float4-groups per image (2^16)
#define NBLK   1024
#define NTHR   256
#define ITERS  2               // 1024*256*2 = 524288 = total float4 groups
#define NBUK   16
#define TSTR   36              // padded float stride: 144 B, 16B-aligned, uniform banks

// ws layout (floats): [NBUK][48] partials; ws[NBUK*48] = block counter (int)
// stat s: 0..15 = p_sum[c], 16..31 = intersection[c], 32..47 = t_sum[c]

__global__ __launch_bounds__(NTHR, 4) void dice_main(
        const float* __restrict__ logits,
        const int*   __restrict__ targets,
        float*       __restrict__ ws,
        float*       __restrict__ out) {
    __shared__ float trans[NTHR * TSTR];   // 36864 B transpose buffer
    __shared__ float partial[4][32];
    __shared__ float tsumw[4][16];
    __shared__ float fin[48];
    __shared__ int   isLast;

    const int tid = threadIdx.x;

    float psum[NC], inter[NC];
    #pragma unroll
    for (int c = 0; c < NC; ++c) { psum[c] = 0.f; inter[c] = 0.f; }
    unsigned cnt[NC];
    #pragma unroll
    for (int c = 0; c < NC; ++c) cnt[c] = 0u;

    const float4* __restrict__ lf4 = reinterpret_cast<const float4*>(logits);
    const int4*   __restrict__ tg4 = reinterpret_cast<const int4*>(targets);

    #pragma unroll 1
    for (int k = 0; k < ITERS; ++k) {
        const int g  = blockIdx.x * NTHR + tid + k * (NBLK * NTHR);
        const int b  = g >> 16;            // g / GPB4
        const int s4 = g & (GPB4 - 1);     // g % GPB4
        const float4* lp = lf4 + (size_t)b * (NC * GPB4) + s4;
        const int4 t = tg4[(size_t)b * GPB4 + s4];

        // 16 independent coalesced float4 loads
        float4 l[NC];
        #pragma unroll
        for (int c = 0; c < NC; ++c) l[c] = lp[(size_t)c * GPB4];

        float sx = 0.f, sy = 0.f, sz = 0.f, sw = 0.f;
        #pragma unroll
        for (int c = 0; c < NC; ++c) {
            l[c].x = __expf(l[c].x); l[c].y = __expf(l[c].y);
            l[c].z = __expf(l[c].z); l[c].w = __expf(l[c].w);
            sx += l[c].x; sy += l[c].y; sz += l[c].z; sw += l[c].w;
        }
        const float ix = __builtin_amdgcn_rcpf(sx);
        const float iy = __builtin_amdgcn_rcpf(sy);
        const float iz = __builtin_amdgcn_rcpf(sz);
        const float iw = __builtin_amdgcn_rcpf(sw);

        #pragma unroll
        for (int c = 0; c < NC; ++c) {
            const float px = l[c].x * ix, py = l[c].y * iy;
            const float pz = l[c].z * iz, pw = l[c].w * iw;
            psum[c] += (px + py) + (pz + pw);
            inter[c] += (t.x == c ? px : 0.f) + (t.y == c ? py : 0.f)
                      + (t.z == c ? pz : 0.f) + (t.w == c ? pw : 0.f);
            // t_sum via wave-uniform ballot counts (no per-lane accumulators)
            cnt[c] += (unsigned)__popcll(__ballot(t.x == c))
                    + (unsigned)__popcll(__ballot(t.y == c))
                    + (unsigned)__popcll(__ballot(t.z == c))
                    + (unsigned)__popcll(__ballot(t.w == c));
        }
    }

    // ---- cheap block reduction: LDS transpose ----
    float* row = &trans[tid * TSTR];
    #pragma unroll
    for (int c = 0; c < NC; ++c) { row[c] = psum[c]; row[NC + c] = inter[c]; }
    if ((tid & 63) == 0) {
        const int wv = tid >> 6;
        #pragma unroll
        for (int c = 0; c < NC; ++c) tsumw[wv][c] = (float)cnt[c] * (1.f / 64.f);
        // cnt was summed over all 64 lanes by ballot, but every lane accumulated
        // the same wave-total; lane0's value is already the wave total. No scale
        // needed -- see correction below.
    }
    __syncthreads();

    const int q = tid >> 6, j = tid & 63;
    if (j < 32) {
        float s = 0.f;
        #pragma unroll 16
        for (int i = 0; i < 64; ++i)
            s += trans[(q * 64 + i) * TSTR + j];
        partial[q][j] = s;
    }
    __syncthreads();

    if (tid < 48) {
        float v;
        if (tid < 32) v = partial[0][tid] + partial[1][tid] + partial[2][tid] + partial[3][tid];
        else {
            const int c = tid - 32;
            v = (tsumw[0][c] + tsumw[1][c] + tsumw[2][c] + tsumw[3][c]) * 64.f;
        }
        atomicAdd(&ws[(blockIdx.x & (NBUK - 1)) * 48 + tid], v);
        __threadfence();
    }
    __syncthreads();

    // ---- last-block finalize ----
    if (tid == 0) {
        const int old = atomicAdd((int*)(ws + NBUK * 48), 1);
        isLast = (old == NBLK - 1);
    }
    __syncthreads();
    if (!isLast) return;

    __threadfence();
    if (tid < 48) {
        float s = 0.f;
        #pragma unroll
        for (int k = 0; k < NBUK; ++k)
            s += atomicAdd(&ws[k * 48 + tid], 0.0f);   // device-scope coherent read
        fin[tid] = s;
    }
    __syncthreads();
    if (tid == 0) {
        float acc = 0.f;
        #pragma unroll
        for (int c = 0; c < NC; ++c) {
            const float dice = (2.f * fin[16 + c] + 1.f) / (fin[c] + fin[32 + c] + 1.f);
            acc += 1.f - dice;
        }
        out[0] = acc * (1.f / 16.f);
    }
}

extern "C" void kernel_launch(void* const* d_in, const int* in_sizes, int n_in,
                              void* d_out, int out_size, void* d_ws, size_t ws_size,
                              hipStream_t stream) {
    const float* logits  = (const float*)d_in[0];
    const int*   targets = (const int*)d_in[1];
    float* ws  = (float*)d_ws;
    float* out = (float*)d_out;

    hipMemsetAsync(ws, 0, 4096, stream);   // buckets + counter
    dice_main<<<NBLK, NTHR, 0, stream>>>(logits, targets, ws, out);
}

// Round 5
// 64.068 us; speedup vs baseline: 1.3751x; 1.0017x over previous
//
#include <hip/hip_runtime.h>

#define HW_    (512*512)       // 262144 pixels per image
#define NC     16
#define GPB4   (HW_/4)         // 65536 float4-groups per image (2^16)
#define NBLK   1024
#define NTHR   256
#define ITERS  2               // 1024*256*2 = 524288 = total float4 groups
#define NBUK   16
#define TSTR   36              // padded float stride: uniform banks, 16B-aligned

// ws layout (floats): [NBUK][48] partials; ws[NBUK*48] = block counter (int)
// stat s: 0..15 = p_sum[c], 16..31 = intersection[c], 32..47 = t_sum[c]

__global__ __launch_bounds__(NTHR) void dice_main(
        const float* __restrict__ logits,
        const int*   __restrict__ targets,
        float*       __restrict__ ws,
        float*       __restrict__ out) {
    __shared__ float trans[NTHR * TSTR];   // 36864 B transpose buffer
    __shared__ float partial[4][32];
    __shared__ float tsumw[4][16];
    __shared__ float fin[48];
    __shared__ int   isLast;

    const int tid = threadIdx.x;

    float psum[NC], inter[NC];
    #pragma unroll
    for (int c = 0; c < NC; ++c) { psum[c] = 0.f; inter[c] = 0.f; }
    unsigned cnt[NC];
    #pragma unroll
    for (int c = 0; c < NC; ++c) cnt[c] = 0u;

    const float4* __restrict__ lf4 = reinterpret_cast<const float4*>(logits);
    const int4*   __restrict__ tg4 = reinterpret_cast<const int4*>(targets);

    #pragma unroll 1
    for (int k = 0; k < ITERS; ++k) {
        const int g  = blockIdx.x * NTHR + tid + k * (NBLK * NTHR);
        const int b  = g >> 16;            // g / GPB4
        const int s4 = g & (GPB4 - 1);     // g % GPB4
        const float4* lp = lf4 + (size_t)b * (NC * GPB4) + s4;

        // ---- issue ALL memory ops first; sched_barrier pins them ahead ----
        const int4 t = tg4[(size_t)b * GPB4 + s4];
        float4 l[NC];
        #pragma unroll
        for (int c = 0; c < NC; ++c) l[c] = lp[(size_t)c * GPB4];
        __builtin_amdgcn_sched_barrier(0);   // 16 loads + targets stay in flight

        float sx = 0.f, sy = 0.f, sz = 0.f, sw = 0.f;
        #pragma unroll
        for (int c = 0; c < NC; ++c) {
            l[c].x = __expf(l[c].x); l[c].y = __expf(l[c].y);
            l[c].z = __expf(l[c].z); l[c].w = __expf(l[c].w);
            sx += l[c].x; sy += l[c].y; sz += l[c].z; sw += l[c].w;
        }
        const float ix = __builtin_amdgcn_rcpf(sx);
        const float iy = __builtin_amdgcn_rcpf(sy);
        const float iz = __builtin_amdgcn_rcpf(sz);
        const float iw = __builtin_amdgcn_rcpf(sw);

        #pragma unroll
        for (int c = 0; c < NC; ++c) {
            const float px = l[c].x * ix, py = l[c].y * iy;
            const float pz = l[c].z * iz, pw = l[c].w * iw;
            psum[c] += (px + py) + (pz + pw);
            inter[c] += (t.x == c ? px : 0.f) + (t.y == c ? py : 0.f)
                      + (t.z == c ? pz : 0.f) + (t.w == c ? pw : 0.f);
            // t_sum via ballot counts (wave-uniform, no extra accumulator reduce)
            cnt[c] += (unsigned)__popcll(__ballot(t.x == c))
                    + (unsigned)__popcll(__ballot(t.y == c))
                    + (unsigned)__popcll(__ballot(t.z == c))
                    + (unsigned)__popcll(__ballot(t.w == c));
        }
    }

    // ---- cheap block reduction: LDS transpose ----
    float* row = &trans[tid * TSTR];
    #pragma unroll
    for (int c = 0; c < NC; ++c) { row[c] = psum[c]; row[NC + c] = inter[c]; }
    if ((tid & 63) == 0) {
        const int wv = tid >> 6;
        #pragma unroll
        for (int c = 0; c < NC; ++c) tsumw[wv][c] = (float)cnt[c];
    }
    __syncthreads();

    const int q = tid >> 6, j = tid & 63;
    if (j < 32) {
        float s = 0.f;
        #pragma unroll 16
        for (int i = 0; i < 64; ++i)
            s += trans[(q * 64 + i) * TSTR + j];
        partial[q][j] = s;
    }
    __syncthreads();

    if (tid < 48) {
        float v;
        if (tid < 32) v = partial[0][tid] + partial[1][tid] + partial[2][tid] + partial[3][tid];
        else {
            const int c = tid - 32;
            v = tsumw[0][c] + tsumw[1][c] + tsumw[2][c] + tsumw[3][c];
        }
        atomicAdd(&ws[(blockIdx.x & (NBUK - 1)) * 48 + tid], v);
        __threadfence();
    }
    __syncthreads();

    // ---- last-block finalize ----
    if (tid == 0) {
        const int old = atomicAdd((int*)(ws + NBUK * 48), 1);
        isLast = (old == NBLK - 1);
    }
    __syncthreads();
    if (!isLast) return;

    __threadfence();
    if (tid < 48) {
        float s = 0.f;
        #pragma unroll
        for (int k = 0; k < NBUK; ++k)
            s += atomicAdd(&ws[k * 48 + tid], 0.0f);   // device-scope coherent read
        fin[tid] = s;
    }
    __syncthreads();
    if (tid == 0) {
        float acc = 0.f;
        #pragma unroll
        for (int c = 0; c < NC; ++c) {
            const float dice = (2.f * fin[16 + c] + 1.f) / (fin[c] + fin[32 + c] + 1.f);
            acc += 1.f - dice;
        }
        out[0] = acc * (1.f / 16.f);
    }
}

extern "C" void kernel_launch(void* const* d_in, const int* in_sizes, int n_in,
                              void* d_out, int out_size, void* d_ws, size_t ws_size,
                              hipStream_t stream) {
    const float* logits  = (const float*)d_in[0];
    const int*   targets = (const int*)d_in[1];
    float* ws  = (float*)d_ws;
    float* out = (float*)d_out;

    hipMemsetAsync(ws, 0, 4096, stream);   // buckets + counter
    dice_main<<<NBLK, NTHR, 0, stream>>>(logits, targets, ws, out);
}

// Round 6
// 43.903 us; speedup vs baseline: 2.0067x; 1.4593x over previous
//
#include <hip/hip_runtime.h>

#define HW_   (512*512)         // 262144 pixels per image
#define NC    16
#define NPIX  (8*HW_)
#define NGRP  (NPIX/4)          // 524288 float4 groups
#define GPB4  (HW_/4)           // 65536 groups per image (2^16)
#define NBLK  512
#define NTHR  256
#define NBUK  16

// ws layout (floats): [NBUK][48] partials; ws[NBUK*48] = block counter (int)
// stat s: 0..15 = p_sum[c], 16..31 = intersection[c], 32..47 = t_sum[c]

__device__ __forceinline__ float wred(float v) {
    v += __shfl_xor(v, 32, 64);
    v += __shfl_xor(v, 16, 64);
    v += __shfl_xor(v,  8, 64);
    v += __shfl_xor(v,  4, 64);
    v += __shfl_xor(v,  2, 64);
    v += __shfl_xor(v,  1, 64);
    return v;
}

__global__ __launch_bounds__(NTHR) void dice_main(
        const float* __restrict__ logits,
        const int*   __restrict__ targets,
        float*       __restrict__ ws,
        float*       __restrict__ out) {
    __shared__ float red[4][48];
    __shared__ float fin[48];
    __shared__ int   isLast;

    float psum[NC], inter[NC], tsum[NC];
    #pragma unroll
    for (int c = 0; c < NC; ++c) { psum[c] = 0.f; inter[c] = 0.f; tsum[c] = 0.f; }

    const int nthreads = NBLK * NTHR;
    for (int g = blockIdx.x * NTHR + threadIdx.x; g < NGRP; g += nthreads) {
        const int b  = g >> 16;        // g / GPB4
        const int s4 = g & (GPB4 - 1); // g % GPB4
        const float4* lp = reinterpret_cast<const float4*>(logits) + (size_t)b * (NC * GPB4) + s4;
        const int4 t = reinterpret_cast<const int4*>(targets)[(size_t)b * GPB4 + s4];

        float4 e[NC];
        float sx = 0.f, sy = 0.f, sz = 0.f, sw = 0.f;
        #pragma unroll
        for (int c = 0; c < NC; ++c) {
            float4 l = lp[(size_t)c * GPB4];
            e[c].x = __expf(l.x); e[c].y = __expf(l.y);
            e[c].z = __expf(l.z); e[c].w = __expf(l.w);
            sx += e[c].x; sy += e[c].y; sz += e[c].z; sw += e[c].w;
        }
        const float ix = __builtin_amdgcn_rcpf(sx);
        const float iy = __builtin_amdgcn_rcpf(sy);
        const float iz = __builtin_amdgcn_rcpf(sz);
        const float iw = __builtin_amdgcn_rcpf(sw);

        #pragma unroll
        for (int c = 0; c < NC; ++c) {
            const float px = e[c].x * ix, py = e[c].y * iy;
            const float pz = e[c].z * iz, pw = e[c].w * iw;
            psum[c] += (px + py) + (pz + pw);
            float ic = 0.f, tc = 0.f;
            if (t.x == c) { ic += px; tc += 1.f; }
            if (t.y == c) { ic += py; tc += 1.f; }
            if (t.z == c) { ic += pz; tc += 1.f; }
            if (t.w == c) { ic += pw; tc += 1.f; }
            inter[c] += ic;
            tsum[c]  += tc;
        }
    }

    // ---- block reduction: per-class wave shuffle-reduce -> LDS (R1 epilogue) ----
    const int tid = threadIdx.x;
    const int lane = tid & 63;
    const int wv   = tid >> 6;
    #pragma unroll
    for (int c = 0; c < NC; ++c) {
        const float a  = wred(psum[c]);
        const float bb = wred(inter[c]);
        const float cc = wred(tsum[c]);
        if (lane == 0) {
            red[wv][c]        = a;
            red[wv][NC + c]   = bb;
            red[wv][2*NC + c] = cc;
        }
    }
    __syncthreads();

    if (tid < 48) {
        const float v = red[0][tid] + red[1][tid] + red[2][tid] + red[3][tid];
        atomicAdd(&ws[(blockIdx.x & (NBUK - 1)) * 48 + tid], v);
        __threadfence();
    }
    __syncthreads();

    // ---- last-block finalize ----
    if (tid == 0) {
        const int old = atomicAdd((int*)(ws + NBUK * 48), 1);
        isLast = (old == NBLK - 1);
    }
    __syncthreads();
    if (!isLast) return;

    __threadfence();
    if (tid < 48) {
        float s = 0.f;
        #pragma unroll
        for (int k = 0; k < NBUK; ++k)
            s += atomicAdd(&ws[k * 48 + tid], 0.0f);   // device-scope coherent read
        fin[tid] = s;
    }
    __syncthreads();
    if (tid == 0) {
        float acc = 0.f;
        #pragma unroll
        for (int c = 0; c < NC; ++c) {
            const float dice = (2.f * fin[NC + c] + 1.f) / (fin[c] + fin[2*NC + c] + 1.f);
            acc += 1.f - dice;
        }
        out[0] = acc * (1.f / 16.f);
    }
}

extern "C" void kernel_launch(void* const* d_in, const int* in_sizes, int n_in,
                              void* d_out, int out_size, void* d_ws, size_t ws_size,
                              hipStream_t stream) {
    const float* logits  = (const float*)d_in[0];
    const int*   targets = (const int*)d_in[1];
    float* ws  = (float*)d_ws;
    float* out = (float*)d_out;

    hipMemsetAsync(ws, 0, 4096, stream);   // buckets + counter
    dice_main<<<NBLK, NTHR, 0, stream>>>(logits, targets, ws, out);
}